// Round 1
// baseline (297.687 us; speedup 1.0000x reference)
//
#include <hip/hip_runtime.h>
#include <cmath>

typedef __attribute__((ext_vector_type(8))) short short8;
typedef __attribute__((ext_vector_type(4))) float floatx4;

#define T_TOK 32768
#define DIMK 512

__device__ __forceinline__ unsigned short f2bf(float f) {
  union { float f; unsigned int u; } v; v.f = f;
  unsigned int r = (v.u + 0x7fffu + ((v.u >> 16) & 1u)) >> 16;
  return (unsigned short)r;
}
__device__ __forceinline__ float bf2f(unsigned short h) {
  union { unsigned int u; float f; } v; v.u = ((unsigned int)h) << 16;
  return v.f;
}

// ---------------- RMSNorm: x (T,512) f32 -> xn bf16 ----------------
__global__ __launch_bounds__(256) void k_rmsnorm(const float* __restrict__ x,
    const float* __restrict__ w, unsigned short* __restrict__ xn) {
  int t = blockIdx.x;
  int tid = threadIdx.x;
  const float2 v = *(const float2*)(x + (size_t)t * DIMK + tid * 2);
  float ss = v.x * v.x + v.y * v.y;
  #pragma unroll
  for (int off = 32; off >= 1; off >>= 1) ss += __shfl_xor(ss, off, 64);
  __shared__ float red[4];
  int wave = tid >> 6, lane = tid & 63;
  if (lane == 0) red[wave] = ss;
  __syncthreads();
  float tot = red[0] + red[1] + red[2] + red[3];
  float scale = rsqrtf(tot * (1.0f / DIMK) + 1e-6f);
  unsigned short o0 = f2bf(v.x * scale * w[tid * 2]);
  unsigned short o1 = f2bf(v.y * scale * w[tid * 2 + 1]);
  unsigned int pack = (unsigned int)o0 | ((unsigned int)o1 << 16);
  *(unsigned int*)(xn + (size_t)t * DIMK + tid * 2) = pack;
}

// ---------------- weight conversion to bf16 ----------------
// Wb rows: [0..511]=wq, [512..767]=wk, [768..1023]=wv (each row 512 wide)
__global__ __launch_bounds__(256) void k_convw(const float* __restrict__ wq,
    const float* __restrict__ wk, const float* __restrict__ wv,
    const float* __restrict__ wo, unsigned short* __restrict__ Wb,
    unsigned short* __restrict__ wob) {
  int i = blockIdx.x * 256 + threadIdx.x;  // grid covers 524288
  float v;
  if (i < 262144) v = wq[i];
  else if (i < 393216) v = wk[i - 262144];
  else v = wv[i - 393216];
  Wb[i] = f2bf(v);
  if (i < 262144) wob[i] = f2bf(wo[i]);
}

// ---------------- RoPE table: (8192 x 32) cos/sin ----------------
__global__ __launch_bounds__(256) void k_rope(float2* __restrict__ rope) {
  int i = blockIdx.x * 256 + threadIdx.x;  // 262144
  int s = i >> 5, m = i & 31;
  double inv = pow(10000.0, -(double)m / 32.0);
  double ang = (double)s * inv;
  rope[i] = make_float2((float)cos(ang), (float)sin(ang));
}

__global__ void k_zero(float* __restrict__ p, int n) {
  int i = blockIdx.x * 256 + threadIdx.x;
  if (i < n) p[i] = 0.f;
}

// ---------------- GEMM: C(M,N) = A(M,512) * Bw(N,512)^T, bf16 in, f32 acc ----------------
template <bool BF16_OUT>
__global__ __launch_bounds__(256) void k_gemm(const unsigned short* __restrict__ A,
    const unsigned short* __restrict__ Bw, void* __restrict__ Cv, int N) {
  constexpr int K = DIMK;
  __shared__ __align__(16) unsigned short As[64 * 72];
  __shared__ __align__(16) unsigned short Bs[64 * 72];
  const int tid = threadIdx.x;
  const int wave = tid >> 6, lane = tid & 63;
  const int r = lane & 15, quad = lane >> 4;
  const int wm = (wave >> 1) * 32, wn = (wave & 1) * 32;
  const int m0 = blockIdx.y * 64, n0 = blockIdx.x * 64;
  const int lrow = tid >> 2;
  const int lcol = (tid & 3) * 16;
  const unsigned short* Ap = A + (size_t)(m0 + lrow) * K + lcol;
  const unsigned short* Bp = Bw + (size_t)(n0 + lrow) * K + lcol;

  floatx4 acc[2][2];
  #pragma unroll
  for (int i = 0; i < 2; i++)
    #pragma unroll
    for (int j = 0; j < 2; j++)
      acc[i][j] = (floatx4){0.f, 0.f, 0.f, 0.f};

  for (int k0 = 0; k0 < K; k0 += 64) {
    uint4 a0 = *(const uint4*)(Ap + k0);
    uint4 a1 = *(const uint4*)(Ap + k0 + 8);
    uint4 b0 = *(const uint4*)(Bp + k0);
    uint4 b1 = *(const uint4*)(Bp + k0 + 8);
    __syncthreads();
    *(uint4*)&As[lrow * 72 + lcol] = a0;
    *(uint4*)&As[lrow * 72 + lcol + 8] = a1;
    *(uint4*)&Bs[lrow * 72 + lcol] = b0;
    *(uint4*)&Bs[lrow * 72 + lcol + 8] = b1;
    __syncthreads();
    #pragma unroll
    for (int kk = 0; kk < 64; kk += 32) {
      short8 af[2], bfv[2];
      #pragma unroll
      for (int i = 0; i < 2; i++)
        af[i] = *(const short8*)&As[(wm + i * 16 + r) * 72 + kk + quad * 8];
      #pragma unroll
      for (int j = 0; j < 2; j++)
        bfv[j] = *(const short8*)&Bs[(wn + j * 16 + r) * 72 + kk + quad * 8];
      #pragma unroll
      for (int i = 0; i < 2; i++)
        #pragma unroll
        for (int j = 0; j < 2; j++)
          acc[i][j] = __builtin_amdgcn_mfma_f32_16x16x32_bf16(af[i], bfv[j], acc[i][j], 0, 0, 0);
    }
  }
  // C/D layout: col = lane&15, row = quad*4 + p  (verified m89/m91)
  #pragma unroll
  for (int i = 0; i < 2; i++)
    #pragma unroll
    for (int j = 0; j < 2; j++) {
      int row = m0 + wm + i * 16 + quad * 4;
      int col = n0 + wn + j * 16 + r;
      #pragma unroll
      for (int p = 0; p < 4; p++) {
        if constexpr (BF16_OUT) {
          ((unsigned short*)Cv)[(size_t)(row + p) * N + col] = f2bf(acc[i][j][p]);
        } else {
          ((float*)Cv)[(size_t)(row + p) * N + col] = acc[i][j][p];
        }
      }
    }
}

// ---------------- KV / Ksum reduction over sequence ----------------
// qkv bf16 (T,1024): q=[0,512), k=[512,768), v=[768,1024)
// KV[bk*64+d] = sum_s phi(rope(k))*v ; Ksum likewise (bk = b*4+kh)
__global__ __launch_bounds__(256) void k_kvred(const unsigned short* __restrict__ qkv,
    const float2* __restrict__ rope, float* __restrict__ KV, float* __restrict__ Ksum) {
  int bk = blockIdx.y;
  int b = bk >> 2, kh = bk & 3;
  int tid = threadIdx.x;
  int m = tid & 31;   // pair index within head_dim
  int sl = tid >> 5;  // 8 slices
  int s0 = blockIdx.x * 256;
  float kvr = 0.f, kvi = 0.f, ksr = 0.f, ksi = 0.f;
  for (int si = sl; si < 256; si += 8) {
    int s = s0 + si;
    size_t t = (size_t)b * 8192 + s;
    const unsigned short* base = qkv + t * 1024;
    unsigned int kp = *(const unsigned int*)(base + 512 + kh * 64 + 2 * m);
    unsigned int vp = *(const unsigned int*)(base + 768 + kh * 64 + 2 * m);
    float kx = bf2f((unsigned short)(kp & 0xffffu));
    float ky = bf2f((unsigned short)(kp >> 16));
    float vx = bf2f((unsigned short)(vp & 0xffffu));
    float vy = bf2f((unsigned short)(vp >> 16));
    float2 cs = rope[s * 32 + m];
    float kr = kx * cs.x - ky * cs.y;
    float ki = kx * cs.y + ky * cs.x;
    kr = kr > 0.f ? kr + 1.f : expf(kr);  // phi = elu + 1
    ki = ki > 0.f ? ki + 1.f : expf(ki);
    kvr += kr * vx; kvi += ki * vy;
    ksr += kr;      ksi += ki;
  }
  __shared__ float red[256 * 4];
  red[tid * 4 + 0] = kvr; red[tid * 4 + 1] = kvi;
  red[tid * 4 + 2] = ksr; red[tid * 4 + 3] = ksi;
  __syncthreads();
  if (sl == 0) {
    for (int q = 1; q < 8; q++) {
      kvr += red[(q * 32 + m) * 4 + 0]; kvi += red[(q * 32 + m) * 4 + 1];
      ksr += red[(q * 32 + m) * 4 + 2]; ksi += red[(q * 32 + m) * 4 + 3];
    }
    atomicAdd(&KV[bk * 64 + 2 * m], kvr);
    atomicAdd(&KV[bk * 64 + 2 * m + 1], kvi);
    atomicAdd(&Ksum[bk * 64 + 2 * m], ksr);
    atomicAdd(&Ksum[bk * 64 + 2 * m + 1], ksi);
  }
}

// ---------------- Q path: rope+phi, Z, Y -> bf16 ----------------
// one block per token, 8 waves = 8 heads, lane = d
__global__ __launch_bounds__(512) void k_qkern(const unsigned short* __restrict__ qkv,
    const float2* __restrict__ rope, const float* __restrict__ KV,
    const float* __restrict__ Ksum, unsigned short* __restrict__ Yb) {
  int t = blockIdx.x;
  int tid = threadIdx.x;
  int h = tid >> 6, lane = tid & 63;
  int b = t >> 13, pos = t & 8191;
  float q = bf2f(qkv[(size_t)t * 1024 + h * 64 + lane]);
  float2 cs = rope[pos * 32 + (lane >> 1)];
  float partner = __shfl_xor(q, 1, 64);
  float qr = ((lane & 1) == 0) ? (q * cs.x - partner * cs.y)
                               : (partner * cs.y + q * cs.x);
  float ql = qr > 0.f ? qr + 1.f : expf(qr);
  int bk = b * 4 + (h >> 1);
  float z = ql * Ksum[bk * 64 + lane];
  #pragma unroll
  for (int off = 32; off >= 1; off >>= 1) z += __shfl_xor(z, off, 64);
  float y = ql * KV[bk * 64 + lane] / (z + 1e-6f);
  Yb[(size_t)t * 512 + h * 64 + lane] = f2bf(y);
}

extern "C" void kernel_launch(void* const* d_in, const int* in_sizes, int n_in,
                              void* d_out, int out_size, void* d_ws, size_t ws_size,
                              hipStream_t stream) {
  const float* x = (const float*)d_in[0];
  const float* norm_w = (const float*)d_in[1];
  const float* wq = (const float*)d_in[2];
  const float* wk = (const float*)d_in[3];
  const float* wv = (const float*)d_in[4];
  const float* wo = (const float*)d_in[5];
  float* out = (float*)d_out;

  char* ws = (char*)d_ws;
  unsigned short* xn  = (unsigned short*)(ws);                  // 33,554,432 B
  unsigned short* Wb  = (unsigned short*)(ws + 33554432);       //  1,048,576 B
  unsigned short* wob = (unsigned short*)(ws + 34603008);       //    524,288 B
  unsigned short* qkv = (unsigned short*)(ws + 35127296);       // 67,108,864 B
  float2* rope        = (float2*)(ws + 102236160);              //  2,097,152 B
  float* KV           = (float*)(ws + 104333312);               //      4,096 B
  float* Ksum         = (float*)(ws + 104337408);               //      4,096 B
  unsigned short* Yb  = (unsigned short*)(ws + 104341504);      // 33,554,432 B
  // total ~137.9 MB

  k_convw<<<2048, 256, 0, stream>>>(wq, wk, wv, wo, Wb, wob);
  k_rmsnorm<<<T_TOK, 256, 0, stream>>>(x, norm_w, xn);
  k_rope<<<1024, 256, 0, stream>>>(rope);
  k_zero<<<8, 256, 0, stream>>>(KV, 2048);  // KV + Ksum are contiguous
  k_gemm<true><<<dim3(16, 512), 256, 0, stream>>>(xn, Wb, (void*)qkv, 1024);
  k_kvred<<<dim3(32, 16), 256, 0, stream>>>(qkv, rope, KV, Ksum);
  k_qkern<<<T_TOK, 512, 0, stream>>>(qkv, rope, KV, Ksum, Yb);
  k_gemm<false><<<dim3(8, 512), 256, 0, stream>>>(Yb, wob, (void*)out, 512);
}

// Round 2
// 285.336 us; speedup vs baseline: 1.0433x; 1.0433x over previous
//
#include <hip/hip_runtime.h>
#include <cmath>

typedef __attribute__((ext_vector_type(8))) short short8;
typedef __attribute__((ext_vector_type(4))) float floatx4;

#define T_TOK 32768
#define DIMK 512

__device__ __forceinline__ unsigned short f2bf(float f) {
  union { float f; unsigned int u; } v; v.f = f;
  unsigned int r = (v.u + 0x7fffu + ((v.u >> 16) & 1u)) >> 16;
  return (unsigned short)r;
}
__device__ __forceinline__ float bf2f(unsigned short h) {
  union { unsigned int u; float f; } v; v.u = ((unsigned int)h) << 16;
  return v.f;
}

// async global->LDS 16B per lane: HW writes lane i at ldsbase + i*16
__device__ __forceinline__ void gload_lds16(const unsigned short* g, unsigned short* ldsbase) {
  __builtin_amdgcn_global_load_lds(
      (const __attribute__((address_space(1))) unsigned int*)g,
      (__attribute__((address_space(3))) unsigned int*)ldsbase, 16, 0, 0);
}

// ---------------- RMSNorm: x (T,512) f32 -> xn bf16 ----------------
__global__ __launch_bounds__(256) void k_rmsnorm(const float* __restrict__ x,
    const float* __restrict__ w, unsigned short* __restrict__ xn) {
  int t = blockIdx.x;
  int tid = threadIdx.x;
  const float2 v = *(const float2*)(x + (size_t)t * DIMK + tid * 2);
  float ss = v.x * v.x + v.y * v.y;
  #pragma unroll
  for (int off = 32; off >= 1; off >>= 1) ss += __shfl_xor(ss, off, 64);
  __shared__ float red[4];
  int wave = tid >> 6, lane = tid & 63;
  if (lane == 0) red[wave] = ss;
  __syncthreads();
  float tot = red[0] + red[1] + red[2] + red[3];
  float scale = rsqrtf(tot * (1.0f / DIMK) + 1e-6f);
  unsigned short o0 = f2bf(v.x * scale * w[tid * 2]);
  unsigned short o1 = f2bf(v.y * scale * w[tid * 2 + 1]);
  unsigned int pack = (unsigned int)o0 | ((unsigned int)o1 << 16);
  *(unsigned int*)(xn + (size_t)t * DIMK + tid * 2) = pack;
}

// ---------------- weight conversion to bf16 ----------------
__global__ __launch_bounds__(256) void k_convw(const float* __restrict__ wq,
    const float* __restrict__ wk, const float* __restrict__ wv,
    const float* __restrict__ wo, unsigned short* __restrict__ Wb,
    unsigned short* __restrict__ wob) {
  int i = blockIdx.x * 256 + threadIdx.x;  // grid covers 524288
  float v;
  if (i < 262144) v = wq[i];
  else if (i < 393216) v = wk[i - 262144];
  else v = wv[i - 393216];
  Wb[i] = f2bf(v);
  if (i < 262144) wob[i] = f2bf(wo[i]);
}

// ---------------- RoPE table: (8192 x 32) cos/sin, no f64 transcendentals --------
// inv[m] = 10000^(-m/32) = 10^(-m/8) = C^m, C = 10^(-1/8); exact double mul chain.
__global__ __launch_bounds__(256) void k_rope(float2* __restrict__ rope) {
  int i = blockIdx.x * 256 + threadIdx.x;  // 262144
  int s = i >> 5, m = i & 31;
  const double c0 = 0.74989420933245582;   // 10^(-1/8)
  double c1 = c0 * c0, c2 = c1 * c1, c3 = c2 * c2, c4 = c3 * c3;
  double v = 1.0;
  if (m & 1)  v *= c0;
  if (m & 2)  v *= c1;
  if (m & 4)  v *= c2;
  if (m & 8)  v *= c3;
  if (m & 16) v *= c4;
  double ang = (double)s * v;
  const double TWO_PI = 6.2831853071795864769;
  double q = rint(ang * (1.0 / TWO_PI));
  double r = fma(-q, TWO_PI, ang);   // |r| <= pi, double-accurate
  float rf = (float)r;
  rope[i] = make_float2(cosf(rf), sinf(rf));
}

__global__ void k_zero(float* __restrict__ p, int n) {
  int i = blockIdx.x * 256 + threadIdx.x;
  if (i < n) p[i] = 0.f;
}

// ---------------- GEMM: C(M,N) = A(M,512) * Bw(N,512)^T ----------------
// m97 structure: 128x128 tile, BK=64, global_load_lds width=16, 4 waves,
// each wave 64x64 = 4x4 16x16x32 bf16 MFMA tiles.
template <bool BF16_OUT>
__global__ __launch_bounds__(256) void k_gemm128(const unsigned short* __restrict__ A,
    const unsigned short* __restrict__ Bw, void* __restrict__ Cv, int N) {
  constexpr int K = DIMK;
  constexpr int BK = 64;
  // UNPADDED (required: global_load_lds writes base + lane*16 contiguously)
  __shared__ __align__(16) unsigned short As[128 * BK];
  __shared__ __align__(16) unsigned short Bs[128 * BK];
  const int tid = threadIdx.x;
  const int wave = tid >> 6, lane = tid & 63;
  const int r = lane & 15, quad = lane >> 4;
  const int wm = (wave >> 1) * 64, wn = (wave & 1) * 64;
  const int m0 = blockIdx.y * 128, n0 = blockIdx.x * 128;

  // staging map (per wave, 4 instrs each for A and B):
  //   lds short-offset of lane = (wave*4+li)*512 + lane*8
  //   => row = (wave*4+li)*8 + (lane>>3), col = (lane&7)*8   [row*64+col flat]
  const int srow = (lane >> 3);        // 0..7 within the 8-row slab
  const int scol = (lane & 7) * 8;     // 0,8,..,56
  const unsigned short* Ag[4];
  const unsigned short* Bg[4];
  unsigned short* Al[4];
  unsigned short* Bl[4];
  #pragma unroll
  for (int li = 0; li < 4; li++) {
    int row = wave * 32 + li * 8 + srow;
    Ag[li] = A  + (size_t)(m0 + row) * K + scol;
    Bg[li] = Bw + (size_t)(n0 + row) * K + scol;
    Al[li] = &As[(wave * 4 + li) * 512];
    Bl[li] = &Bs[(wave * 4 + li) * 512];
  }

  floatx4 acc[4][4];
  #pragma unroll
  for (int i = 0; i < 4; i++)
    #pragma unroll
    for (int j = 0; j < 4; j++)
      acc[i][j] = (floatx4){0.f, 0.f, 0.f, 0.f};

  for (int k0 = 0; k0 < K; k0 += BK) {
    #pragma unroll
    for (int li = 0; li < 4; li++) {
      gload_lds16(Ag[li] + k0, Al[li]);
      gload_lds16(Bg[li] + k0, Bl[li]);
    }
    __syncthreads();  // drains vmcnt(0): async LDS writes complete
    #pragma unroll
    for (int kk = 0; kk < BK; kk += 32) {
      short8 af[4], bfv[4];
      #pragma unroll
      for (int i = 0; i < 4; i++)
        af[i] = *(const short8*)&As[(wm + i * 16 + r) * BK + kk + quad * 8];
      #pragma unroll
      for (int j = 0; j < 4; j++)
        bfv[j] = *(const short8*)&Bs[(wn + j * 16 + r) * BK + kk + quad * 8];
      #pragma unroll
      for (int i = 0; i < 4; i++)
        #pragma unroll
        for (int j = 0; j < 4; j++)
          acc[i][j] = __builtin_amdgcn_mfma_f32_16x16x32_bf16(af[i], bfv[j], acc[i][j], 0, 0, 0);
    }
    __syncthreads();  // compute done before next overwrite
  }
  // C/D layout: col = lane&15, row = quad*4 + p  (verified m89/m91)
  #pragma unroll
  for (int i = 0; i < 4; i++)
    #pragma unroll
    for (int j = 0; j < 4; j++) {
      int row = m0 + wm + i * 16 + quad * 4;
      int col = n0 + wn + j * 16 + r;
      #pragma unroll
      for (int p = 0; p < 4; p++) {
        if constexpr (BF16_OUT) {
          ((unsigned short*)Cv)[(size_t)(row + p) * N + col] = f2bf(acc[i][j][p]);
        } else {
          ((float*)Cv)[(size_t)(row + p) * N + col] = acc[i][j][p];
        }
      }
    }
}

// ---------------- KV / Ksum reduction over sequence ----------------
__global__ __launch_bounds__(256) void k_kvred(const unsigned short* __restrict__ qkv,
    const float2* __restrict__ rope, float* __restrict__ KV, float* __restrict__ Ksum) {
  int bk = blockIdx.y;
  int b = bk >> 2, kh = bk & 3;
  int tid = threadIdx.x;
  int m = tid & 31;
  int sl = tid >> 5;
  int s0 = blockIdx.x * 256;
  float kvr = 0.f, kvi = 0.f, ksr = 0.f, ksi = 0.f;
  for (int si = sl; si < 256; si += 8) {
    int s = s0 + si;
    size_t t = (size_t)b * 8192 + s;
    const unsigned short* base = qkv + t * 1024;
    unsigned int kp = *(const unsigned int*)(base + 512 + kh * 64 + 2 * m);
    unsigned int vp = *(const unsigned int*)(base + 768 + kh * 64 + 2 * m);
    float kx = bf2f((unsigned short)(kp & 0xffffu));
    float ky = bf2f((unsigned short)(kp >> 16));
    float vx = bf2f((unsigned short)(vp & 0xffffu));
    float vy = bf2f((unsigned short)(vp >> 16));
    float2 cs = rope[s * 32 + m];
    float kr = kx * cs.x - ky * cs.y;
    float ki = kx * cs.y + ky * cs.x;
    kr = kr > 0.f ? kr + 1.f : expf(kr);
    ki = ki > 0.f ? ki + 1.f : expf(ki);
    kvr += kr * vx; kvi += ki * vy;
    ksr += kr;      ksi += ki;
  }
  __shared__ float red[256 * 4];
  red[tid * 4 + 0] = kvr; red[tid * 4 + 1] = kvi;
  red[tid * 4 + 2] = ksr; red[tid * 4 + 3] = ksi;
  __syncthreads();
  if (sl == 0) {
    for (int q = 1; q < 8; q++) {
      kvr += red[(q * 32 + m) * 4 + 0]; kvi += red[(q * 32 + m) * 4 + 1];
      ksr += red[(q * 32 + m) * 4 + 2]; ksi += red[(q * 32 + m) * 4 + 3];
    }
    atomicAdd(&KV[bk * 64 + 2 * m], kvr);
    atomicAdd(&KV[bk * 64 + 2 * m + 1], kvi);
    atomicAdd(&Ksum[bk * 64 + 2 * m], ksr);
    atomicAdd(&Ksum[bk * 64 + 2 * m + 1], ksi);
  }
}

// ---------------- Q path: rope+phi, Z, Y -> bf16 ----------------
__global__ __launch_bounds__(512) void k_qkern(const unsigned short* __restrict__ qkv,
    const float2* __restrict__ rope, const float* __restrict__ KV,
    const float* __restrict__ Ksum, unsigned short* __restrict__ Yb) {
  int t = blockIdx.x;
  int tid = threadIdx.x;
  int h = tid >> 6, lane = tid & 63;
  int b = t >> 13, pos = t & 8191;
  float q = bf2f(qkv[(size_t)t * 1024 + h * 64 + lane]);
  float2 cs = rope[pos * 32 + (lane >> 1)];
  float partner = __shfl_xor(q, 1, 64);
  float qr = ((lane & 1) == 0) ? (q * cs.x - partner * cs.y)
                               : (partner * cs.y + q * cs.x);
  float ql = qr > 0.f ? qr + 1.f : expf(qr);
  int bk = b * 4 + (h >> 1);
  float z = ql * Ksum[bk * 64 + lane];
  #pragma unroll
  for (int off = 32; off >= 1; off >>= 1) z += __shfl_xor(z, off, 64);
  float y = ql * KV[bk * 64 + lane] / (z + 1e-6f);
  Yb[(size_t)t * 512 + h * 64 + lane] = f2bf(y);
}

extern "C" void kernel_launch(void* const* d_in, const int* in_sizes, int n_in,
                              void* d_out, int out_size, void* d_ws, size_t ws_size,
                              hipStream_t stream) {
  const float* x = (const float*)d_in[0];
  const float* norm_w = (const float*)d_in[1];
  const float* wq = (const float*)d_in[2];
  const float* wk = (const float*)d_in[3];
  const float* wv = (const float*)d_in[4];
  const float* wo = (const float*)d_in[5];
  float* out = (float*)d_out;

  char* ws = (char*)d_ws;
  unsigned short* xn  = (unsigned short*)(ws);                  // 33,554,432 B
  unsigned short* Wb  = (unsigned short*)(ws + 33554432);       //  1,048,576 B
  unsigned short* wob = (unsigned short*)(ws + 34603008);       //    524,288 B
  unsigned short* qkv = (unsigned short*)(ws + 35127296);       // 67,108,864 B
  float2* rope        = (float2*)(ws + 102236160);              //  2,097,152 B
  float* KV           = (float*)(ws + 104333312);               //      4,096 B
  float* Ksum         = (float*)(ws + 104337408);               //      4,096 B
  unsigned short* Yb  = (unsigned short*)(ws + 104341504);      // 33,554,432 B

  k_convw<<<2048, 256, 0, stream>>>(wq, wk, wv, wo, Wb, wob);
  k_rmsnorm<<<T_TOK, 256, 0, stream>>>(x, norm_w, xn);
  k_rope<<<1024, 256, 0, stream>>>(rope);
  k_zero<<<8, 256, 0, stream>>>(KV, 2048);
  k_gemm128<true><<<dim3(8, 256), 256, 0, stream>>>(xn, Wb, (void*)qkv, 1024);
  k_kvred<<<dim3(32, 16), 256, 0, stream>>>(qkv, rope, KV, Ksum);
  k_qkern<<<T_TOK, 512, 0, stream>>>(qkv, rope, KV, Ksum, Yb);
  k_gemm128<false><<<dim3(4, 256), 256, 0, stream>>>(Yb, wob, (void*)out, 512);
}